// Round 1
// baseline (106.203 us; speedup 1.0000x reference)
//
#include <hip/hip_runtime.h>

#define B_    2
#define NFEAT 3
#define NCH   4
#define DIMX  18
#define NPT   (18*18*18)          /* 5832 */
#define JS    16
#define CHUNK ((NPT + JS - 1)/JS) /* 365 */
#define IB    ((NPT + 255)/256)   /* 23 */

// sqrt(log2(e)) / ALPHA  (ALPHA == BETA == 5)
#define FSC   (1.2011224087864498f / 5.0f)

__device__ __forceinline__ float blockReduceSum(float v) {
  #pragma unroll
  for (int o = 32; o > 0; o >>= 1) v += __shfl_down(v, o, 64);
  __shared__ float red[4];
  int wid = threadIdx.x >> 6, lane = threadIdx.x & 63;
  if (lane == 0) red[wid] = v;
  __syncthreads();
  v = (threadIdx.x < 4) ? red[threadIdx.x] : 0.0f;
  if (wid == 0) {
    v += __shfl_down(v, 2, 64);
    v += __shfl_down(v, 1, 64);
  }
  return v;  // valid on thread 0
}

// P1 record (8 floats): f0..f5, q, pad      (features pre-scaled by sqrt(log2 e)/5)
// H  record (4 floats): softmax(U) channels
__global__ void prep_kernel(const float* __restrict__ I, const float* __restrict__ U,
                            float* __restrict__ P1, float* __restrict__ H) {
  int idx = blockIdx.x * blockDim.x + threadIdx.x;
  if (idx >= B_ * NPT) return;
  int b = idx / NPT, n = idx - b * NPT;
  int x = n / (DIMX * DIMX);
  int rem = n - x * DIMX * DIMX;
  int y = rem / DIMX, z = rem - y * DIMX;

  float f0 = x * FSC, f1 = y * FSC, f2 = z * FSC;
  float f3 = I[(size_t)(b * NFEAT + 0) * NPT + n] * FSC;
  float f4 = I[(size_t)(b * NFEAT + 1) * NPT + n] * FSC;
  float f5 = I[(size_t)(b * NFEAT + 2) * NPT + n] * FSC;
  float q = -0.5f * (f0*f0 + f1*f1 + f2*f2 + f3*f3 + f4*f4 + f5*f5);

  float4* P = (float4*)(P1 + (size_t)idx * 8);
  P[0] = make_float4(f0, f1, f2, f3);
  P[1] = make_float4(f4, f5, q, 0.0f);

  float u0 = U[(size_t)(b * NCH + 0) * NPT + n];
  float u1 = U[(size_t)(b * NCH + 1) * NPT + n];
  float u2 = U[(size_t)(b * NCH + 2) * NPT + n];
  float u3 = U[(size_t)(b * NCH + 3) * NPT + n];
  float m = fmaxf(fmaxf(u0, u1), fmaxf(u2, u3));
  float e0 = __expf(u0 - m), e1 = __expf(u1 - m), e2 = __expf(u2 - m), e3 = __expf(u3 - m);
  float inv = 1.0f / (e0 + e1 + e2 + e3);
  ((float4*)(H + (size_t)idx * 4))[0] = make_float4(e0*inv, e1*inv, e2*inv, e3*inv);
}

// Pass 1: s_i = sum_j exp2(min(q_i + q_j + f_i.f_j, 0)); partial over j-split.
__global__ void __launch_bounds__(256) pass1_kernel(const float* __restrict__ P1,
                                                    float* __restrict__ part) {
  __shared__ float4 sh[512];
  int b = blockIdx.z;
  int i = blockIdx.x * 256 + threadIdx.x;
  bool valid = i < NPT;
  int ic = valid ? i : NPT - 1;
  const float4* Pb = (const float4*)(P1 + (size_t)b * NPT * 8);
  float4 a0 = Pb[(size_t)ic * 2], a1 = Pb[(size_t)ic * 2 + 1];
  float fi0 = a0.x, fi1 = a0.y, fi2 = a0.z, fi3 = a0.w, fi4 = a1.x, fi5 = a1.y, qi = a1.z;

  int jstart = blockIdx.y * CHUNK;
  int jend = min(jstart + CHUNK, NPT);
  float acc = 0.0f;
  for (int t = jstart; t < jend; t += 256) {
    int jj = t + threadIdx.x;
    if (jj < jend) {
      sh[threadIdx.x * 2]     = Pb[(size_t)jj * 2];
      sh[threadIdx.x * 2 + 1] = Pb[(size_t)jj * 2 + 1];
    }
    __syncthreads();
    int kmax = min(256, jend - t);
    if (kmax == 256) {
      #pragma unroll 8
      for (int k = 0; k < 256; ++k) {
        float4 fa = sh[k * 2], fb = sh[k * 2 + 1];
        float arg = qi + fb.z + fi0*fa.x + fi1*fa.y + fi2*fa.z + fi3*fa.w + fi4*fb.x + fi5*fb.y;
        acc += exp2f(fminf(arg, 0.0f));
      }
    } else {
      for (int k = 0; k < kmax; ++k) {
        float4 fa = sh[k * 2], fb = sh[k * 2 + 1];
        float arg = qi + fb.z + fi0*fa.x + fi1*fa.y + fi2*fa.z + fi3*fa.w + fi4*fb.x + fi5*fb.y;
        acc += exp2f(fminf(arg, 0.0f));
      }
    }
    __syncthreads();
  }
  if (valid) part[((size_t)b * JS + blockIdx.y) * NPT + i] = acc;
}

// Finalize norm; build P2 record (12 floats): f0..f5, q, pad, v0..v3 (v = H*norm)
// and G record (4 floats): (1-H)*norm
__global__ void finalize_kernel(const float* __restrict__ P1, const float* __restrict__ H,
                                const float* __restrict__ part,
                                float* __restrict__ P2, float* __restrict__ G) {
  int idx = blockIdx.x * blockDim.x + threadIdx.x;
  if (idx >= B_ * NPT) return;
  int b = idx / NPT, i = idx - b * NPT;
  float s = 0.0f;
  #pragma unroll
  for (int k = 0; k < JS; ++k) s += part[((size_t)b * JS + k) * NPT + i];
  float nrm = rsqrtf(s + 1e-20f);
  float4 a0 = ((const float4*)(P1 + (size_t)idx * 8))[0];
  float4 a1 = ((const float4*)(P1 + (size_t)idx * 8))[1];
  float4 h  = ((const float4*)(H  + (size_t)idx * 4))[0];
  float4* P = (float4*)(P2 + (size_t)idx * 12);
  P[0] = a0;
  P[1] = a1;
  P[2] = make_float4(h.x * nrm, h.y * nrm, h.z * nrm, h.w * nrm);
  ((float4*)(G + (size_t)idx * 4))[0] =
      make_float4((1.0f - h.x) * nrm, (1.0f - h.y) * nrm, (1.0f - h.z) * nrm, (1.0f - h.w) * nrm);
}

// Pass 2: acc_c = sum_j w_ij * v_cj ; block partial loss = sum_i sum_c acc_c * g_ci
__global__ void __launch_bounds__(256) pass2_kernel(const float* __restrict__ P2,
                                                    const float* __restrict__ G,
                                                    float* __restrict__ partialLoss) {
  __shared__ float4 sh[768];
  int b = blockIdx.z;
  int i = blockIdx.x * 256 + threadIdx.x;
  bool valid = i < NPT;
  int ic = valid ? i : NPT - 1;
  const float4* Pb = (const float4*)(P2 + (size_t)b * NPT * 12);
  float4 a0 = Pb[(size_t)ic * 3], a1 = Pb[(size_t)ic * 3 + 1];
  float fi0 = a0.x, fi1 = a0.y, fi2 = a0.z, fi3 = a0.w, fi4 = a1.x, fi5 = a1.y, qi = a1.z;
  float4 g = ((const float4*)(G + ((size_t)b * NPT + ic) * 4))[0];

  int jstart = blockIdx.y * CHUNK;
  int jend = min(jstart + CHUNK, NPT);
  float acc0 = 0.0f, acc1 = 0.0f, acc2 = 0.0f, acc3 = 0.0f;
  for (int t = jstart; t < jend; t += 256) {
    int jj = t + threadIdx.x;
    if (jj < jend) {
      sh[threadIdx.x * 3]     = Pb[(size_t)jj * 3];
      sh[threadIdx.x * 3 + 1] = Pb[(size_t)jj * 3 + 1];
      sh[threadIdx.x * 3 + 2] = Pb[(size_t)jj * 3 + 2];
    }
    __syncthreads();
    int kmax = min(256, jend - t);
    if (kmax == 256) {
      #pragma unroll 4
      for (int k = 0; k < 256; ++k) {
        float4 fa = sh[k * 3], fb = sh[k * 3 + 1], fv = sh[k * 3 + 2];
        float arg = qi + fb.z + fi0*fa.x + fi1*fa.y + fi2*fa.z + fi3*fa.w + fi4*fb.x + fi5*fb.y;
        float w = exp2f(fminf(arg, 0.0f));
        acc0 += w * fv.x; acc1 += w * fv.y; acc2 += w * fv.z; acc3 += w * fv.w;
      }
    } else {
      for (int k = 0; k < kmax; ++k) {
        float4 fa = sh[k * 3], fb = sh[k * 3 + 1], fv = sh[k * 3 + 2];
        float arg = qi + fb.z + fi0*fa.x + fi1*fa.y + fi2*fa.z + fi3*fa.w + fi4*fb.x + fi5*fb.y;
        float w = exp2f(fminf(arg, 0.0f));
        acc0 += w * fv.x; acc1 += w * fv.y; acc2 += w * fv.z; acc3 += w * fv.w;
      }
    }
    __syncthreads();
  }
  float t_ = valid ? (acc0 * g.x + acc1 * g.y + acc2 * g.z + acc3 * g.w) : 0.0f;
  float r = blockReduceSum(t_);
  if (threadIdx.x == 0)
    partialLoss[((size_t)b * JS + blockIdx.y) * IB + blockIdx.x] = r;
}

__global__ void reduce_kernel(const float* __restrict__ partialLoss, int n,
                              float* __restrict__ out) {
  float v = 0.0f;
  for (int k = threadIdx.x; k < n; k += 256) v += partialLoss[k];
  float r = blockReduceSum(v);
  if (threadIdx.x == 0) out[0] = r;
}

extern "C" void kernel_launch(void* const* d_in, const int* in_sizes, int n_in,
                              void* d_out, int out_size, void* d_ws, size_t ws_size,
                              hipStream_t stream) {
  const float* I = (const float*)d_in[0];
  const float* U = (const float*)d_in[1];
  float* out = (float*)d_out;
  float* ws = (float*)d_ws;

  size_t off = 0;
  float* P1 = ws + off;  off += (size_t)B_ * NPT * 8;
  float* H  = ws + off;  off += (size_t)B_ * NPT * 4;
  float* pt = ws + off;  off += (size_t)B_ * JS * NPT;
  float* P2 = ws + off;  off += (size_t)B_ * NPT * 12;
  float* G  = ws + off;  off += (size_t)B_ * NPT * 4;
  float* pl = ws + off;  off += (size_t)B_ * JS * IB;

  prep_kernel<<<(B_ * NPT + 255) / 256, 256, 0, stream>>>(I, U, P1, H);
  dim3 grid(IB, JS, B_);
  pass1_kernel<<<grid, 256, 0, stream>>>(P1, pt);
  finalize_kernel<<<(B_ * NPT + 255) / 256, 256, 0, stream>>>(P1, H, pt, P2, G);
  pass2_kernel<<<grid, 256, 0, stream>>>(P2, G, pl);
  reduce_kernel<<<1, 256, 0, stream>>>(pl, B_ * JS * IB, out);
}